// Round 14
// baseline (81.566 us; speedup 1.0000x reference)
//
#include <hip/hip_runtime.h>

// DR splitting solver. BATCH=4096, N=96 (64 x + 32 s), M=48 (16 eq + 32 ineq).
// JF and Hessian are batch-independent => prox_g1 is an affine map y = P x + Bmat p.
//   S=(I+Q)^{-1}; T=S Jx^T; K2=Jx T+diag(0,I32); R2=K2^{-1}[T^T|E];
//   P=diag(S,I)-[T;E^T]R2; Bmat=[-P[:,:64] | R2^T]
// Iterate 10x: y=Px+c; x += clamp(2y-x,l,u)-y; out=y[:64].
//
// Round-13 lesson: 192 VGPRs of P can never fit the ~132 budget the compiler
// grants at 384 threads -- P was silently re-streamed from L2 every iteration
// in ALL round-9..13 iter variants. Round-14: K-SPLIT iter -- each thread owns
// 2 P-rows x ONE K-half (12 quads = 96 VGPR, fits!), partial dots reduced via
// LDS. 384 thr, EB=8, 512 blocks = 2 blocks/CU, 12 waves/CU.
// prep = proven round-9 shape (42us, VGPR 104), untouched.

__device__ __forceinline__ float dot4f(float4 a, float4 b) {
  return a.x*b.x + a.y*b.y + a.z*b.z + a.w*b.w;
}
__device__ __forceinline__ void ld4(const float* p, float* d) {
  float4 v = *(const float4*)p;
  d[0] = v.x; d[1] = v.y; d[2] = v.z; d[3] = v.w;
}
__device__ __forceinline__ void st4(float* p, const float* s) {
  *(float4*)p = make_float4(s[0], s[1], s[2], s[3]);
}
__device__ __forceinline__ float fastrcp(float x) {
  float r = __builtin_amdgcn_rcpf(x);
  return r * (2.0f - x * r);     // 1 Newton step: ~1e-7 rel
}
// W = A*B (4x4)
__device__ __forceinline__ void mm4(float W[4][4], const float A[4][4], const float B[4][4]) {
  #pragma unroll
  for (int r = 0; r < 4; ++r)
    #pragma unroll
    for (int q = 0; q < 4; ++q) {
      float s = A[r][0]*B[0][q];
      #pragma unroll
      for (int k = 1; k < 4; ++k) s += A[r][k]*B[k][q];
      W[r][q] = s;
    }
}
// in-place 4x4 inverse by GJ, no pivoting (SPD principal blocks)
__device__ __forceinline__ void inv4(float D[4][4]) {
  #pragma unroll
  for (int p = 0; p < 4; ++p) {
    float pi = fastrcp(D[p][p]);
    D[p][p] = pi;
    #pragma unroll
    for (int q = 0; q < 4; ++q) if (q != p) D[p][q] *= pi;
    #pragma unroll
    for (int i = 0; i < 4; ++i) if (i != p) {
      float f = D[i][p];
      #pragma unroll
      for (int q = 0; q < 4; ++q) if (q != p) D[i][q] -= f * D[p][q];
      D[i][p] = -f * pi;
    }
  }
}

// one double-buffered block-GJ step, stride 68 (64x64), all 256 threads
__device__ __forceinline__ void gj_step64(const float* __restrict__ src,
                                          float* __restrict__ dst,
                                          int b, int ig, int jg) {
  float D[4][4], C[4][4], R[4][4], T4[4][4], W[4][4];
  #pragma unroll
  for (int r = 0; r < 4; ++r) {
    ld4(&src[(4*b + r)*68 + 4*b],  D[r]);
    ld4(&src[(4*ig + r)*68 + 4*b], C[r]);
    ld4(&src[(4*b + r)*68 + 4*jg], R[r]);
    ld4(&src[(4*ig + r)*68 + 4*jg], T4[r]);
  }
  inv4(D);
  if (ig == b) {
    if (jg == b) {
      #pragma unroll
      for (int r = 0; r < 4; ++r)
        #pragma unroll
        for (int q = 0; q < 4; ++q) W[r][q] = D[r][q];
    } else {
      mm4(W, D, R);
    }
  } else {
    float E[4][4];
    mm4(E, C, D);
    if (jg == b) {
      #pragma unroll
      for (int r = 0; r < 4; ++r)
        #pragma unroll
        for (int q = 0; q < 4; ++q) W[r][q] = -E[r][q];
    } else {
      #pragma unroll
      for (int r = 0; r < 4; ++r)
        #pragma unroll
        for (int q = 0; q < 4; ++q) {
          float s = T4[r][q];
          #pragma unroll
          for (int k = 0; k < 4; ++k) s -= E[r][k] * R[k][q];
          W[r][q] = s;
        }
    }
  }
  #pragma unroll
  for (int r = 0; r < 4; ++r) st4(&dst[(4*ig + r)*68 + 4*jg], W[r]);
  __syncthreads();
}

// one double-buffered block-GJ step, stride 52 (48x48), threads 0..143 active
__device__ __forceinline__ void gj_step48(const float* __restrict__ src,
                                          float* __restrict__ dst,
                                          int b, int tid) {
  const bool act = tid < 144;
  const int ig = tid / 12, jg = tid - (tid / 12) * 12;
  float D[4][4], C[4][4], R[4][4], T4[4][4], W[4][4];
  if (act) {
    #pragma unroll
    for (int r = 0; r < 4; ++r) {
      ld4(&src[(4*b + r)*52 + 4*b],  D[r]);
      ld4(&src[(4*ig + r)*52 + 4*b], C[r]);
      ld4(&src[(4*b + r)*52 + 4*jg], R[r]);
      ld4(&src[(4*ig + r)*52 + 4*jg], T4[r]);
    }
    inv4(D);
    if (ig == b) {
      if (jg == b) {
        #pragma unroll
        for (int r = 0; r < 4; ++r)
          #pragma unroll
          for (int q = 0; q < 4; ++q) W[r][q] = D[r][q];
      } else {
        mm4(W, D, R);
      }
    } else {
      float E[4][4];
      mm4(E, C, D);
      if (jg == b) {
        #pragma unroll
        for (int r = 0; r < 4; ++r)
          #pragma unroll
          for (int q = 0; q < 4; ++q) W[r][q] = -E[r][q];
      } else {
        #pragma unroll
        for (int r = 0; r < 4; ++r)
          #pragma unroll
          for (int q = 0; q < 4; ++q) {
            float s = T4[r][q];
            #pragma unroll
            for (int k = 0; k < 4; ++k) s -= E[r][k] * R[k][q];
            W[r][q] = s;
          }
      }
    }
    #pragma unroll
    for (int r = 0; r < 4; ++r) st4(&dst[(4*ig + r)*52 + 4*jg], W[r]);
  }
  __syncthreads();
}

// ---------------------------------------------------------------- kernel A
__global__ __launch_bounds__(256, 1) void prep_kernel(
    const float* __restrict__ Qg, const float* __restrict__ Ag,
    const float* __restrict__ Gg,
    float* __restrict__ Pg, float* __restrict__ Bg)
{
  // floats: 4352 + 4352 + 2496 + 4608 = 15808 = 63232 B
  __shared__ float sMa[64*68];   // M1 ping  -> S (after 16 steps)
  __shared__ float sMb[64*68];   // M1 pong  -> T (64x48, stride 48)
  __shared__ float sK [48*52];   // K2 ping  -> Ki
  __shared__ float sR2[48*96];   // Jx (s68) -> K2 pong (s52) -> R2 (s96)

#define SM_(i,j) sMa[(i)*68+(j)]
#define TT_(i,j) sMb[(i)*48+(j)]
#define SK_(i,j) sK[(i)*52+(j)]
#define JX_(a,k) sR2[(a)*68+(k)]

  const int tid = threadIdx.x;
  const int ig = tid >> 4, jg = tid & 15;

  // ---- stage Jx = [A;G] (48x64, stride 68) and M1 = Q + I
  {
    const float4* A4 = (const float4*)Ag;          // 256 quads
    const float4* G4 = (const float4*)Gg;          // 512 quads
    {
      int t = tid;
      int a = t >> 4, kc = t & 15;
      st4(&JX_(a, kc*4), (const float*)&A4[t]);
    }
    for (int t = tid; t < 512; t += 256) {
      int a = t >> 4, kc = t & 15;
      st4(&JX_(16 + a, kc*4), (const float*)&G4[t]);
    }
    const float4* Q4 = (const float4*)Qg;          // 1024 quads
    for (int t = tid; t < 1024; t += 256) {
      int i = t >> 4, kc = t & 15;
      st4(&SM_(i, kc*4), (const float*)&Q4[t]);
    }
  }
  __syncthreads();
  if (tid < 64) SM_(tid, tid) += 1.0f;
  __syncthreads();

  // ---- block-GJ 64 (dbuf, 1 barrier/step, 16 steps) -> S in sMa
  #pragma unroll 1
  for (int p = 0; p < 8; ++p) {
    gj_step64(sMa, sMb, 2*p,     ig, jg);
    gj_step64(sMb, sMa, 2*p + 1, ig, jg);
  }

  // ---- T = S Jx^T : 4x3 register tile/thread (16 ig x 16 jg covers 64x48)
  {
    const int i0 = 4*ig, j0 = 3*jg;
    float acc[4][3] = {};
    #pragma unroll 4
    for (int kq = 0; kq < 16; ++kq) {
      float sv[4][4], jv[3][4];
      ld4(&SM_(i0+0, kq*4), sv[0]); ld4(&SM_(i0+1, kq*4), sv[1]);
      ld4(&SM_(i0+2, kq*4), sv[2]); ld4(&SM_(i0+3, kq*4), sv[3]);
      ld4(&JX_(j0+0, kq*4), jv[0]); ld4(&JX_(j0+1, kq*4), jv[1]);
      ld4(&JX_(j0+2, kq*4), jv[2]);
      #pragma unroll
      for (int r = 0; r < 4; ++r)
        #pragma unroll
        for (int c = 0; c < 3; ++c)
          #pragma unroll
          for (int s = 0; s < 4; ++s)
            acc[r][c] += sv[r][s] * jv[c][s];
    }
    __syncthreads();   // SM/JX reads done before TT writes to sMb pong
    #pragma unroll
    for (int r = 0; r < 4; ++r)
      #pragma unroll
      for (int c = 0; c < 3; ++c)
        TT_(i0+r, j0+c) = acc[r][c];
  }
  __syncthreads();

  // ---- K2 = Jx T + diag(0,I32)  (192 threads, 3x4 tiles)
  if (tid < 192) {
    int ag = tid / 12, bg = tid - ag*12;
    int a0 = ag*3, b0 = bg*4;
    float acc[3][4] = {};
    #pragma unroll 4
    for (int k = 0; k < 64; ++k) {
      float4 tb = *(const float4*)&TT_(k,b0);
      #pragma unroll
      for (int r = 0; r < 3; ++r) {
        float jv = JX_(a0 + r, k);
        acc[r][0] += jv*tb.x; acc[r][1] += jv*tb.y;
        acc[r][2] += jv*tb.z; acc[r][3] += jv*tb.w;
      }
    }
    #pragma unroll
    for (int r = 0; r < 3; ++r)
      #pragma unroll
      for (int q = 0; q < 4; ++q) {
        int a = a0 + r, b = b0 + q;
        SK_(a,b) = acc[r][q] + ((a == b && a >= 16) ? 1.0f : 0.0f);
      }
  }
  __syncthreads();

  // ---- block-GJ 48 (dbuf; pong overlays dead Jx region) -> Ki in sK
  {
    float* KP = sR2;   // 48*52 = 2496 <= 4608
    #pragma unroll 1
    for (int p = 0; p < 6; ++p) {
      gj_step48(sK, KP, 2*p,     tid);
      gj_step48(KP, sK, 2*p + 1, tid);
    }
  }
  // KP / JX dead; sR2 region becomes R2 (stride 96).

  // ---- R2 cols<64: R2[k][c] = sum_m Ki[k][m]*T[c][m]  (3k x 4c tiles)
  {
    int kg = tid >> 4, cg = tid & 15;
    int k0 = kg*3, c0 = cg*4;
    float acc[3][4] = {};
    #pragma unroll 4
    for (int m = 0; m < 48; m += 4) {
      float kv[3][4], tv[4][4];
      ld4(&SK_(k0+0,m), kv[0]); ld4(&SK_(k0+1,m), kv[1]); ld4(&SK_(k0+2,m), kv[2]);
      ld4(&TT_(c0+0,m), tv[0]); ld4(&TT_(c0+1,m), tv[1]);
      ld4(&TT_(c0+2,m), tv[2]); ld4(&TT_(c0+3,m), tv[3]);
      #pragma unroll
      for (int r = 0; r < 3; ++r)
        #pragma unroll
        for (int q = 0; q < 4; ++q)
          #pragma unroll
          for (int s = 0; s < 4; ++s)
            acc[r][q] += kv[r][s] * tv[q][s];
    }
    #pragma unroll
    for (int r = 0; r < 3; ++r)
      #pragma unroll
      for (int q = 0; q < 4; ++q) {
        int k = k0 + r, c = c0 + q;
        float v = acc[r][q];
        sR2[k*96 + c] = v;
        Bg[c*112 + 64 + k] = v;       // Bmat[:,64:] = R2^T
      }
  }
  // R2 cols>=64 (selection from Ki)
  #pragma unroll 1
  for (int t = tid; t < 48*32; t += 256) {
    int k = t >> 5, j = t & 31;
    float v = SK_(k, 16 + j);
    sR2[k*96 + 64 + j] = v;
    Bg[(64 + j)*112 + 64 + k] = v;
  }
  __syncthreads();

  // ---- P heavy rows (i<64): P = S_diag - T*R2  (16 ig x 24 jc tasks)
  #pragma unroll 1
  for (int task = tid; task < 384; task += 256) {
    int tg = task / 24, jc = task - tg*24;
    int i0 = tg*4, j0 = jc*4;
    float acc[4][4];
    #pragma unroll
    for (int r = 0; r < 4; ++r)
      #pragma unroll
      for (int q = 0; q < 4; ++q)
        acc[r][q] = (j0 < 64) ? SM_(i0+r, j0+q) : 0.0f;
    #pragma unroll 4
    for (int m = 0; m < 48; m += 4) {
      float tv[4][4], rv[4][4];
      ld4(&TT_(i0+0,m), tv[0]); ld4(&TT_(i0+1,m), tv[1]);
      ld4(&TT_(i0+2,m), tv[2]); ld4(&TT_(i0+3,m), tv[3]);
      ld4(&sR2[(m+0)*96 + j0], rv[0]);
      ld4(&sR2[(m+1)*96 + j0], rv[1]);
      ld4(&sR2[(m+2)*96 + j0], rv[2]);
      ld4(&sR2[(m+3)*96 + j0], rv[3]);
      #pragma unroll
      for (int r = 0; r < 4; ++r)
        #pragma unroll
        for (int q = 0; q < 4; ++q)
          #pragma unroll
          for (int s = 0; s < 4; ++s)
            acc[r][q] -= tv[r][s] * rv[s][q];
    }
    #pragma unroll
    for (int r = 0; r < 4; ++r)
      #pragma unroll
      for (int q = 0; q < 4; ++q) {
        int i = i0 + r, j = j0 + q;
        float v = acc[r][q];
        Pg[i*96 + j] = v;
        if (j0 < 64) Bg[i*112 + j] = -v;   // Bmat[:,:64] = -P[:,:64]
      }
  }
  // ---- P rows >= 64: P[64+a][j] = (64+a==j) - R2[16+a][j]
  #pragma unroll 1
  for (int t = tid; t < 32*96; t += 256) {
    int a = t / 96, j = t - (t / 96) * 96;
    float v = ((64 + a) == j ? 1.0f : 0.0f) - sR2[(16 + a)*96 + j];
    Pg[(64 + a)*96 + j] = v;
    if (j < 64) Bg[(64 + a)*112 + j] = -v;
  }
#undef SM_
#undef TT_
#undef SK_
#undef JX_
}

// ---------------------------------------------------------------- kernel B
#define EB 8   // elements per block; grid = 512 blocks x 384 threads (2/CU)

__global__ __launch_bounds__(384, 1) void iter_kernel(
    const float* __restrict__ xg, const float* __restrict__ pg,
    const float* __restrict__ Pg, const float* __restrict__ Bg,
    float* __restrict__ outg)
{
  // K-SPLIT: thread (kh 0..1, eg 0..3, rg 0..47) owns P rows {2rg,2rg+1}
  // restricted to K-half kh: 2 x 12 quads = 96 VGPR -> actually fits the
  // budget, so P is register-resident (rounds 9-13 silently re-streamed it).
  // Partial dots reduced through sPart; kh=0 threads apply the prox update.
  __shared__ float sX[2][EB][100];
  __shared__ float sPart[2][EB][96];
  __shared__ float sPar[EB][112];

  const int tid = threadIdx.x;          // 0..383
  const int gbase = blockIdx.x * EB;
  const int kh  = tid / 192;            // 0..1 K-half
  const int rem = tid - 192 * kh;
  const int eg  = rem / 48;             // 0..3
  const int rg  = rem - 48 * eg;        // 0..47
  const int e0 = 2 * eg, r0 = 2 * rg;
  const int kq0 = kh * 12;              // first quad of my K-half

  // stage x (192 quads) and parms (224 quads)
  const float4* X4 = (const float4*)xg;
  if (tid < 192) {
    int e = tid / 24, kc = tid - 24 * (tid / 24);
    *(float4*)&sX[0][e][kc*4] = X4[gbase*24 + tid];
  }
  const float4* Par4 = (const float4*)pg;
  if (tid < 224) {
    int e = tid / 28, jc = tid - 28 * (tid / 28);
    *(float4*)&sPar[e][jc*4] = Par4[gbase*28 + tid];
  }

  // my half-rows of P -> registers (96 VGPR total)
  float4 pA[12], pB[12];
  const float4* P4 = (const float4*)Pg;
  #pragma unroll
  for (int q = 0; q < 12; ++q) pA[q] = P4[r0*24 + kq0 + q];
  #pragma unroll
  for (int q = 0; q < 12; ++q) pB[q] = P4[(r0+1)*24 + kq0 + q];

  __syncthreads();

  // partial c: Bmat rows r0,r0+1, columns [56*kh, 56*kh+56) (14 quads)
  float c00 = 0.f, c01 = 0.f, c10 = 0.f, c11 = 0.f;
  {
    const float4* B4 = (const float4*)Bg;
    #pragma unroll 4
    for (int jc = 14*kh; jc < 14*kh + 14; ++jc) {
      float4 b0 = B4[r0*28 + jc];
      float4 b1 = B4[(r0+1)*28 + jc];
      float4 q0 = *(const float4*)&sPar[e0    ][jc*4];
      float4 q1 = *(const float4*)&sPar[e0 + 1][jc*4];
      c00 += dot4f(b0, q0); c01 += dot4f(b0, q1);
      c10 += dot4f(b1, q0); c11 += dot4f(b1, q1);
    }
  }

  const float lo = (r0 < 64) ? -1000.0f : 0.0f;
  const float* curb = &sX[0][0][0];
  float* nxtb = &sX[1][0][0];

  #pragma unroll 1
  for (int it = 0; it < 10; ++it) {
    // partial dot over my K-half (P register-resident, x from LDS broadcast)
    float a00 = c00, a01 = c01, a10 = c10, a11 = c11;
    const float* x0p = curb + e0 * 100 + kq0 * 4;
    const float* x1p = x0p + 100;
    float4 x0 = *(const float4*)(x0p);
    float4 x1 = *(const float4*)(x1p);
    #pragma unroll
    for (int q = 0; q < 12; ++q) {
      float4 nx0, nx1;
      if (q < 11) {                      // 1-ahead prefetch
        nx0 = *(const float4*)(x0p + (q+1)*4);
        nx1 = *(const float4*)(x1p + (q+1)*4);
      }
      a00 += dot4f(pA[q], x0); a01 += dot4f(pA[q], x1);
      a10 += dot4f(pB[q], x0); a11 += dot4f(pB[q], x1);
      if (q < 11) { x0 = nx0; x1 = nx1; }
    }
    // publish partials (2-way bank aliasing only -> free)
    *(float2*)&sPart[kh][e0    ][r0] = make_float2(a00, a10);
    *(float2*)&sPart[kh][e0 + 1][r0] = make_float2(a01, a11);
    __syncthreads();

    if (it < 9) {
      if (kh == 0) {
        #pragma unroll
        for (int ee = 0; ee < 2; ++ee) {
          int e = e0 + ee;
          float2 pa = *(const float2*)&sPart[0][e][r0];
          float2 pb = *(const float2*)&sPart[1][e][r0];
          float y0 = pa.x + pb.x;        // row r0
          float y1 = pa.y + pb.y;        // row r0+1
          float2 xo = *(const float2*)(curb + e*100 + r0);
          float z0 = fminf(fmaxf(2.f*y0 - xo.x, lo), 1000.f);
          float z1 = fminf(fmaxf(2.f*y1 - xo.y, lo), 1000.f);
          *(float2*)(nxtb + e*100 + r0) =
              make_float2(xo.x + z0 - y0, xo.y + z1 - y1);
        }
      }
      __syncthreads();
      float* t = (float*)curb; curb = nxtb; nxtb = t;
    } else {
      if (kh == 0 && r0 < 64) {
        #pragma unroll
        for (int ee = 0; ee < 2; ++ee) {
          int e = e0 + ee;
          float2 pa = *(const float2*)&sPart[0][e][r0];
          float2 pb = *(const float2*)&sPart[1][e][r0];
          *(float2*)&outg[(gbase + e)*64 + r0] =
              make_float2(pa.x + pb.x, pa.y + pb.y);
        }
      }
    }
  }
}

// ---------------------------------------------------------------- launch
extern "C" void kernel_launch(void* const* d_in, const int* in_sizes, int n_in,
                              void* d_out, int out_size, void* d_ws, size_t ws_size,
                              hipStream_t stream) {
  const float* x     = (const float*)d_in[0];   // (4096, 96)
  const float* parms = (const float*)d_in[1];   // (4096, 112)
  const float* Qg    = (const float*)d_in[2];   // (64, 64)
  const float* Ag    = (const float*)d_in[3];   // (16, 64)
  const float* Gg    = (const float*)d_in[4];   // (32, 64)
  float* out = (float*)d_out;                   // (4096, 64)

  float* ws  = (float*)d_ws;
  float* Pg  = ws;               // 96*96  = 9216
  float* Bg  = ws + 9216;        // 96*112 = 10752

  prep_kernel<<<1, 256, 0, stream>>>(Qg, Ag, Gg, Pg, Bg);
  iter_kernel<<<4096 / EB, 384, 0, stream>>>(x, parms, Pg, Bg, out);
}

// Round 15
// 61.209 us; speedup vs baseline: 1.3326x; 1.3326x over previous
//
#include <hip/hip_runtime.h>

// DR splitting solver. BATCH=4096, N=96 (64 x + 32 s), M=48 (16 eq + 32 ineq).
// JF and Hessian are batch-independent => prox_g1 is an affine map y = P x + Bmat p.
//   S=(I+Q)^{-1}; T=S Jx^T; K2=Jx T+diag(0,I32); R2=K2^{-1}[T^T|E];
//   P=diag(S,I)-[T;E^T]R2; Bmat=[-P[:,:64] | R2^T]
// Iterate 10x: y=Px+c; x += clamp(2y-x,l,u)-y; out=y[:64].
//
// Round-14 lesson: every fp32-VALU iter formulation (r9-r14) is stuck at
// ~31-42us -- the allocator never grants enough VGPRs for resident P, and
// streaming P is issue/latency-bound at this problem's low occupancy.
// Round-15: MFMA iter. y=Px per block is a 96x16x96 matmul -> split-bf16
// (P=Phi+Plo, x=xhi+xlo, 3 products ~= 16-bit mantissa; DR map nonexpansive,
// threshold 0.148 >> ~1e-3 error). Wave w owns row-tile 16w: P-frags = 24
// VGPRs total. 9 MFMA/wave/iter replaces 384 FMA + 48 LDS reads/thread.
// prep = proven round-9 shape (42us, VGPR 104), untouched.

typedef __attribute__((ext_vector_type(8))) short short8v;
typedef __attribute__((ext_vector_type(4))) float float4v;

__device__ __forceinline__ float dot4f(float4 a, float4 b) {
  return a.x*b.x + a.y*b.y + a.z*b.z + a.w*b.w;
}
__device__ __forceinline__ void ld4(const float* p, float* d) {
  float4 v = *(const float4*)p;
  d[0] = v.x; d[1] = v.y; d[2] = v.z; d[3] = v.w;
}
__device__ __forceinline__ void st4(float* p, const float* s) {
  *(float4*)p = make_float4(s[0], s[1], s[2], s[3]);
}
__device__ __forceinline__ float fastrcp(float x) {
  float r = __builtin_amdgcn_rcpf(x);
  return r * (2.0f - x * r);     // 1 Newton step: ~1e-7 rel
}
// W = A*B (4x4)
__device__ __forceinline__ void mm4(float W[4][4], const float A[4][4], const float B[4][4]) {
  #pragma unroll
  for (int r = 0; r < 4; ++r)
    #pragma unroll
    for (int q = 0; q < 4; ++q) {
      float s = A[r][0]*B[0][q];
      #pragma unroll
      for (int k = 1; k < 4; ++k) s += A[r][k]*B[k][q];
      W[r][q] = s;
    }
}
// in-place 4x4 inverse by GJ, no pivoting (SPD principal blocks)
__device__ __forceinline__ void inv4(float D[4][4]) {
  #pragma unroll
  for (int p = 0; p < 4; ++p) {
    float pi = fastrcp(D[p][p]);
    D[p][p] = pi;
    #pragma unroll
    for (int q = 0; q < 4; ++q) if (q != p) D[p][q] *= pi;
    #pragma unroll
    for (int i = 0; i < 4; ++i) if (i != p) {
      float f = D[i][p];
      #pragma unroll
      for (int q = 0; q < 4; ++q) if (q != p) D[i][q] -= f * D[p][q];
      D[i][p] = -f * pi;
    }
  }
}

// bf16 split helpers (RNE)
__device__ __forceinline__ unsigned short bf16h_rne(float v) {
  unsigned u = __float_as_uint(v);
  unsigned r = u + 0x7FFFu + ((u >> 16) & 1u);
  return (unsigned short)(r >> 16);
}
__device__ __forceinline__ float bf16_back(unsigned short h) {
  return __uint_as_float(((unsigned)h) << 16);
}
__device__ __forceinline__ void split8(const float v[8], short8v &hi, short8v &lo) {
  #pragma unroll
  for (int j = 0; j < 8; ++j) {
    unsigned short h = bf16h_rne(v[j]);
    float res = v[j] - bf16_back(h);
    unsigned short l = bf16h_rne(res);
    hi[j] = (short)h;
    lo[j] = (short)l;
  }
}

// one double-buffered block-GJ step, stride 68 (64x64), all 256 threads
__device__ __forceinline__ void gj_step64(const float* __restrict__ src,
                                          float* __restrict__ dst,
                                          int b, int ig, int jg) {
  float D[4][4], C[4][4], R[4][4], T4[4][4], W[4][4];
  #pragma unroll
  for (int r = 0; r < 4; ++r) {
    ld4(&src[(4*b + r)*68 + 4*b],  D[r]);
    ld4(&src[(4*ig + r)*68 + 4*b], C[r]);
    ld4(&src[(4*b + r)*68 + 4*jg], R[r]);
    ld4(&src[(4*ig + r)*68 + 4*jg], T4[r]);
  }
  inv4(D);
  if (ig == b) {
    if (jg == b) {
      #pragma unroll
      for (int r = 0; r < 4; ++r)
        #pragma unroll
        for (int q = 0; q < 4; ++q) W[r][q] = D[r][q];
    } else {
      mm4(W, D, R);
    }
  } else {
    float E[4][4];
    mm4(E, C, D);
    if (jg == b) {
      #pragma unroll
      for (int r = 0; r < 4; ++r)
        #pragma unroll
        for (int q = 0; q < 4; ++q) W[r][q] = -E[r][q];
    } else {
      #pragma unroll
      for (int r = 0; r < 4; ++r)
        #pragma unroll
        for (int q = 0; q < 4; ++q) {
          float s = T4[r][q];
          #pragma unroll
          for (int k = 0; k < 4; ++k) s -= E[r][k] * R[k][q];
          W[r][q] = s;
        }
    }
  }
  #pragma unroll
  for (int r = 0; r < 4; ++r) st4(&dst[(4*ig + r)*68 + 4*jg], W[r]);
  __syncthreads();
}

// one double-buffered block-GJ step, stride 52 (48x48), threads 0..143 active
__device__ __forceinline__ void gj_step48(const float* __restrict__ src,
                                          float* __restrict__ dst,
                                          int b, int tid) {
  const bool act = tid < 144;
  const int ig = tid / 12, jg = tid - (tid / 12) * 12;
  float D[4][4], C[4][4], R[4][4], T4[4][4], W[4][4];
  if (act) {
    #pragma unroll
    for (int r = 0; r < 4; ++r) {
      ld4(&src[(4*b + r)*52 + 4*b],  D[r]);
      ld4(&src[(4*ig + r)*52 + 4*b], C[r]);
      ld4(&src[(4*b + r)*52 + 4*jg], R[r]);
      ld4(&src[(4*ig + r)*52 + 4*jg], T4[r]);
    }
    inv4(D);
    if (ig == b) {
      if (jg == b) {
        #pragma unroll
        for (int r = 0; r < 4; ++r)
          #pragma unroll
          for (int q = 0; q < 4; ++q) W[r][q] = D[r][q];
      } else {
        mm4(W, D, R);
      }
    } else {
      float E[4][4];
      mm4(E, C, D);
      if (jg == b) {
        #pragma unroll
        for (int r = 0; r < 4; ++r)
          #pragma unroll
          for (int q = 0; q < 4; ++q) W[r][q] = -E[r][q];
      } else {
        #pragma unroll
        for (int r = 0; r < 4; ++r)
          #pragma unroll
          for (int q = 0; q < 4; ++q) {
            float s = T4[r][q];
            #pragma unroll
            for (int k = 0; k < 4; ++k) s -= E[r][k] * R[k][q];
            W[r][q] = s;
          }
      }
    }
    #pragma unroll
    for (int r = 0; r < 4; ++r) st4(&dst[(4*ig + r)*52 + 4*jg], W[r]);
  }
  __syncthreads();
}

// ---------------------------------------------------------------- kernel A
__global__ __launch_bounds__(256, 1) void prep_kernel(
    const float* __restrict__ Qg, const float* __restrict__ Ag,
    const float* __restrict__ Gg,
    float* __restrict__ Pg, float* __restrict__ Bg)
{
  // floats: 4352 + 4352 + 2496 + 4608 = 15808 = 63232 B
  __shared__ float sMa[64*68];   // M1 ping  -> S (after 16 steps)
  __shared__ float sMb[64*68];   // M1 pong  -> T (64x48, stride 48)
  __shared__ float sK [48*52];   // K2 ping  -> Ki
  __shared__ float sR2[48*96];   // Jx (s68) -> K2 pong (s52) -> R2 (s96)

#define SM_(i,j) sMa[(i)*68+(j)]
#define TT_(i,j) sMb[(i)*48+(j)]
#define SK_(i,j) sK[(i)*52+(j)]
#define JX_(a,k) sR2[(a)*68+(k)]

  const int tid = threadIdx.x;
  const int ig = tid >> 4, jg = tid & 15;

  // ---- stage Jx = [A;G] (48x64, stride 68) and M1 = Q + I
  {
    const float4* A4 = (const float4*)Ag;          // 256 quads
    const float4* G4 = (const float4*)Gg;          // 512 quads
    {
      int t = tid;
      int a = t >> 4, kc = t & 15;
      st4(&JX_(a, kc*4), (const float*)&A4[t]);
    }
    for (int t = tid; t < 512; t += 256) {
      int a = t >> 4, kc = t & 15;
      st4(&JX_(16 + a, kc*4), (const float*)&G4[t]);
    }
    const float4* Q4 = (const float4*)Qg;          // 1024 quads
    for (int t = tid; t < 1024; t += 256) {
      int i = t >> 4, kc = t & 15;
      st4(&SM_(i, kc*4), (const float*)&Q4[t]);
    }
  }
  __syncthreads();
  if (tid < 64) SM_(tid, tid) += 1.0f;
  __syncthreads();

  // ---- block-GJ 64 (dbuf, 1 barrier/step, 16 steps) -> S in sMa
  #pragma unroll 1
  for (int p = 0; p < 8; ++p) {
    gj_step64(sMa, sMb, 2*p,     ig, jg);
    gj_step64(sMb, sMa, 2*p + 1, ig, jg);
  }

  // ---- T = S Jx^T : 4x3 register tile/thread (16 ig x 16 jg covers 64x48)
  {
    const int i0 = 4*ig, j0 = 3*jg;
    float acc[4][3] = {};
    #pragma unroll 4
    for (int kq = 0; kq < 16; ++kq) {
      float sv[4][4], jv[3][4];
      ld4(&SM_(i0+0, kq*4), sv[0]); ld4(&SM_(i0+1, kq*4), sv[1]);
      ld4(&SM_(i0+2, kq*4), sv[2]); ld4(&SM_(i0+3, kq*4), sv[3]);
      ld4(&JX_(j0+0, kq*4), jv[0]); ld4(&JX_(j0+1, kq*4), jv[1]);
      ld4(&JX_(j0+2, kq*4), jv[2]);
      #pragma unroll
      for (int r = 0; r < 4; ++r)
        #pragma unroll
        for (int c = 0; c < 3; ++c)
          #pragma unroll
          for (int s = 0; s < 4; ++s)
            acc[r][c] += sv[r][s] * jv[c][s];
    }
    __syncthreads();   // SM/JX reads done before TT writes to sMb pong
    #pragma unroll
    for (int r = 0; r < 4; ++r)
      #pragma unroll
      for (int c = 0; c < 3; ++c)
        TT_(i0+r, j0+c) = acc[r][c];
  }
  __syncthreads();

  // ---- K2 = Jx T + diag(0,I32)  (192 threads, 3x4 tiles)
  if (tid < 192) {
    int ag = tid / 12, bg = tid - ag*12;
    int a0 = ag*3, b0 = bg*4;
    float acc[3][4] = {};
    #pragma unroll 4
    for (int k = 0; k < 64; ++k) {
      float4 tb = *(const float4*)&TT_(k,b0);
      #pragma unroll
      for (int r = 0; r < 3; ++r) {
        float jv = JX_(a0 + r, k);
        acc[r][0] += jv*tb.x; acc[r][1] += jv*tb.y;
        acc[r][2] += jv*tb.z; acc[r][3] += jv*tb.w;
      }
    }
    #pragma unroll
    for (int r = 0; r < 3; ++r)
      #pragma unroll
      for (int q = 0; q < 4; ++q) {
        int a = a0 + r, b = b0 + q;
        SK_(a,b) = acc[r][q] + ((a == b && a >= 16) ? 1.0f : 0.0f);
      }
  }
  __syncthreads();

  // ---- block-GJ 48 (dbuf; pong overlays dead Jx region) -> Ki in sK
  {
    float* KP = sR2;   // 48*52 = 2496 <= 4608
    #pragma unroll 1
    for (int p = 0; p < 6; ++p) {
      gj_step48(sK, KP, 2*p,     tid);
      gj_step48(KP, sK, 2*p + 1, tid);
    }
  }
  // KP / JX dead; sR2 region becomes R2 (stride 96).

  // ---- R2 cols<64: R2[k][c] = sum_m Ki[k][m]*T[c][m]  (3k x 4c tiles)
  {
    int kg = tid >> 4, cg = tid & 15;
    int k0 = kg*3, c0 = cg*4;
    float acc[3][4] = {};
    #pragma unroll 4
    for (int m = 0; m < 48; m += 4) {
      float kv[3][4], tv[4][4];
      ld4(&SK_(k0+0,m), kv[0]); ld4(&SK_(k0+1,m), kv[1]); ld4(&SK_(k0+2,m), kv[2]);
      ld4(&TT_(c0+0,m), tv[0]); ld4(&TT_(c0+1,m), tv[1]);
      ld4(&TT_(c0+2,m), tv[2]); ld4(&TT_(c0+3,m), tv[3]);
      #pragma unroll
      for (int r = 0; r < 3; ++r)
        #pragma unroll
        for (int q = 0; q < 4; ++q)
          #pragma unroll
          for (int s = 0; s < 4; ++s)
            acc[r][q] += kv[r][s] * tv[q][s];
    }
    #pragma unroll
    for (int r = 0; r < 3; ++r)
      #pragma unroll
      for (int q = 0; q < 4; ++q) {
        int k = k0 + r, c = c0 + q;
        float v = acc[r][q];
        sR2[k*96 + c] = v;
        Bg[c*112 + 64 + k] = v;       // Bmat[:,64:] = R2^T
      }
  }
  // R2 cols>=64 (selection from Ki)
  #pragma unroll 1
  for (int t = tid; t < 48*32; t += 256) {
    int k = t >> 5, j = t & 31;
    float v = SK_(k, 16 + j);
    sR2[k*96 + 64 + j] = v;
    Bg[(64 + j)*112 + 64 + k] = v;
  }
  __syncthreads();

  // ---- P heavy rows (i<64): P = S_diag - T*R2  (16 ig x 24 jc tasks)
  #pragma unroll 1
  for (int task = tid; task < 384; task += 256) {
    int tg = task / 24, jc = task - tg*24;
    int i0 = tg*4, j0 = jc*4;
    float acc[4][4];
    #pragma unroll
    for (int r = 0; r < 4; ++r)
      #pragma unroll
      for (int q = 0; q < 4; ++q)
        acc[r][q] = (j0 < 64) ? SM_(i0+r, j0+q) : 0.0f;
    #pragma unroll 4
    for (int m = 0; m < 48; m += 4) {
      float tv[4][4], rv[4][4];
      ld4(&TT_(i0+0,m), tv[0]); ld4(&TT_(i0+1,m), tv[1]);
      ld4(&TT_(i0+2,m), tv[2]); ld4(&TT_(i0+3,m), tv[3]);
      ld4(&sR2[(m+0)*96 + j0], rv[0]);
      ld4(&sR2[(m+1)*96 + j0], rv[1]);
      ld4(&sR2[(m+2)*96 + j0], rv[2]);
      ld4(&sR2[(m+3)*96 + j0], rv[3]);
      #pragma unroll
      for (int r = 0; r < 4; ++r)
        #pragma unroll
        for (int q = 0; q < 4; ++q)
          #pragma unroll
          for (int s = 0; s < 4; ++s)
            acc[r][q] -= tv[r][s] * rv[s][q];
    }
    #pragma unroll
    for (int r = 0; r < 4; ++r)
      #pragma unroll
      for (int q = 0; q < 4; ++q) {
        int i = i0 + r, j = j0 + q;
        float v = acc[r][q];
        Pg[i*96 + j] = v;
        if (j0 < 64) Bg[i*112 + j] = -v;   // Bmat[:,:64] = -P[:,:64]
      }
  }
  // ---- P rows >= 64: P[64+a][j] = (64+a==j) - R2[16+a][j]
  #pragma unroll 1
  for (int t = tid; t < 32*96; t += 256) {
    int a = t / 96, j = t - (t / 96) * 96;
    float v = ((64 + a) == j ? 1.0f : 0.0f) - sR2[(16 + a)*96 + j];
    Pg[(64 + a)*96 + j] = v;
    if (j < 64) Bg[(64 + a)*112 + j] = -v;
  }
#undef SM_
#undef TT_
#undef SK_
#undef JX_
}

// ---------------------------------------------------------------- kernel B
#define EB 16   // elements per block; grid = 256 blocks x 384 threads (6 waves)

__global__ __launch_bounds__(384, 1) void iter_kernel(
    const float* __restrict__ xg, const float* __restrict__ pg,
    const float* __restrict__ Pg, const float* __restrict__ Bg,
    float* __restrict__ outg)
{
  // MFMA formulation: per block Y[96][16] = P[96][96] @ X[96][16] in
  // split-bf16 (3 products). Wave w owns row-tile 16w. Fragment layouts
  // (cdna4_isa §10, m89-verified D): A[row=lane&15][k=8*(lane>>4)+j],
  // B[k=8*(lane>>4)+j][col=lane&15], D[row=4*(lane>>4)+reg][col=lane&15].
  __shared__ float sX[2][EB][100];
  __shared__ float sPar[EB][128];   // parms padded to K=128 with zeros

  const int tid   = threadIdx.x;    // 0..383
  const int gbase = blockIdx.x * EB;
  const int w     = tid >> 6;       // wave 0..5 -> rows 16w..16w+15
  const int lane  = tid & 63;
  const int e     = lane & 15;      // elem (B col / D col / A row-within-tile)
  const int g     = lane >> 4;      // 0..3 (k-group / D row-group)
  const int row0  = 16 * w;

  // ---- stage x (384 quads, exactly 1/thread)
  {
    int ee = tid / 24, kc = tid - 24 * (tid / 24);
    *(float4*)&sX[0][ee][kc*4] = ((const float4*)xg)[gbase*24 + tid];
  }
  // ---- stage parms (448 quads) + zero-pad cols 112..127
  for (int t = tid; t < EB*28; t += 384) {
    int ee = t / 28, jc = t - 28 * (t / 28);
    *(float4*)&sPar[ee][jc*4] = ((const float4*)pg)[gbase*28 + t];
  }
  if (tid < EB*4) {
    int ee = tid >> 2, jc = tid & 3;
    *(float4*)&sPar[ee][112 + jc*4] = make_float4(0.f, 0.f, 0.f, 0.f);
  }

  // ---- P fragments (A operand), hi/lo, register-resident (24 VGPRs)
  short8v pfh[3], pfl[3];
  #pragma unroll
  for (int kc = 0; kc < 3; ++kc) {
    float v[8];
    const float* src = Pg + (row0 + e)*96 + 32*kc + 8*g;
    ld4(src, v); ld4(src + 4, v + 4);
    split8(v, pfh[kc], pfl[kc]);
  }

  __syncthreads();   // x + parms staged

  // ---- c = Bmat @ parms via MFMA (K=112 zero-padded to 128)
  float4v cfrag = {0.f, 0.f, 0.f, 0.f};
  #pragma unroll
  for (int kc = 0; kc < 4; ++kc) {
    const int kbase = 32*kc + 8*g;
    float v[8];
    short8v ah, al, bh, bl;
    if (kbase < 112) {
      const float* src = Bg + (row0 + e)*112 + kbase;
      ld4(src, v); ld4(src + 4, v + 4);
    } else {
      #pragma unroll
      for (int j = 0; j < 8; ++j) v[j] = 0.f;
    }
    split8(v, ah, al);
    ld4(&sPar[e][kbase], v); ld4(&sPar[e][kbase + 4], v + 4);
    split8(v, bh, bl);
    cfrag = __builtin_amdgcn_mfma_f32_16x16x32_bf16(ah, bh, cfrag, 0, 0, 0);
    cfrag = __builtin_amdgcn_mfma_f32_16x16x32_bf16(ah, bl, cfrag, 0, 0, 0);
    cfrag = __builtin_amdgcn_mfma_f32_16x16x32_bf16(al, bh, cfrag, 0, 0, 0);
  }

  const float lob = (row0 < 64) ? -1000.f : 0.f;   // tile rows all same side
  float* curb = &sX[0][0][0];
  float* nxtb = &sX[1][0][0];

  #pragma unroll 1
  for (int it = 0; it < 10; ++it) {
    // build x fragments (B operand) from current x, split-bf16
    float4v acc = cfrag;
    short8v xh[3], xl[3];
    #pragma unroll
    for (int kc = 0; kc < 3; ++kc) {
      float v[8];
      const float* src = curb + e*100 + 32*kc + 8*g;
      ld4(src, v); ld4(src + 4, v + 4);
      split8(v, xh[kc], xl[kc]);
    }
    #pragma unroll
    for (int kc = 0; kc < 3; ++kc) {
      acc = __builtin_amdgcn_mfma_f32_16x16x32_bf16(pfh[kc], xh[kc], acc, 0, 0, 0);
      acc = __builtin_amdgcn_mfma_f32_16x16x32_bf16(pfh[kc], xl[kc], acc, 0, 0, 0);
      acc = __builtin_amdgcn_mfma_f32_16x16x32_bf16(pfl[kc], xh[kc], acc, 0, 0, 0);
    }
    if (it < 9) {
      // prox + x update (each wave writes only its own 16 rows)
      #pragma unroll
      for (int r = 0; r < 4; ++r) {
        int row = row0 + 4*g + r;
        float y  = acc[r];
        float xo = curb[e*100 + row];
        float z  = fminf(fmaxf(2.f*y - xo, lob), 1000.f);
        nxtb[e*100 + row] = xo + z - y;
      }
      __syncthreads();
      float* t2 = curb; curb = nxtb; nxtb = t2;
    } else {
      if (row0 < 64) {
        *(float4*)&outg[(gbase + e)*64 + row0 + 4*g] =
            make_float4(acc[0], acc[1], acc[2], acc[3]);
      }
    }
  }
}

// ---------------------------------------------------------------- launch
extern "C" void kernel_launch(void* const* d_in, const int* in_sizes, int n_in,
                              void* d_out, int out_size, void* d_ws, size_t ws_size,
                              hipStream_t stream) {
  const float* x     = (const float*)d_in[0];   // (4096, 96)
  const float* parms = (const float*)d_in[1];   // (4096, 112)
  const float* Qg    = (const float*)d_in[2];   // (64, 64)
  const float* Ag    = (const float*)d_in[3];   // (16, 64)
  const float* Gg    = (const float*)d_in[4];   // (32, 64)
  float* out = (float*)d_out;                   // (4096, 64)

  float* ws  = (float*)d_ws;
  float* Pg  = ws;               // 96*96  = 9216
  float* Bg  = ws + 9216;        // 96*112 = 10752

  prep_kernel<<<1, 256, 0, stream>>>(Qg, Ag, Gg, Pg, Bg);
  iter_kernel<<<4096 / EB, 384, 0, stream>>>(x, parms, Pg, Bg, out);
}

// Round 16
// 59.743 us; speedup vs baseline: 1.3653x; 1.0245x over previous
//
#include <hip/hip_runtime.h>

// DR splitting solver. BATCH=4096, N=96 (64 x + 32 s), M=48 (16 eq + 32 ineq).
// prox_g1 is an affine map y = P x + Bmat p (JF/Hessian batch-independent).
//   S=(I+Q)^{-1}; T=S Jx^T; K2=Jx T+diag(0,I32); R2=K2^{-1}[T^T|E];
//   P=diag(S,I)-[T;E^T]R2; Bmat=[-P[:,:64] | R2^T]
// Iterate 10x: y=Px+c; x += clamp(2y-x,l,u)-y; out=y[:64].
//
// Round-15: MFMA split-bf16 iter = 19us (worked). prep (42us, 69% of total) now
// split: prep1 = serial {GJ64,T,K2,GJ48} on 1 block -> S,T,Ki to ws;
// prep2 = 4 blocks, each redoes R2 in LDS (cheap) + its 24-row slice of P/Bmat.
// This parallelizes the tail AND instruments the serial-vs-tail split.
// iter micro: 9-deep MFMA acc chain -> 3 independent 3-deep chains.

typedef __attribute__((ext_vector_type(8))) short short8v;
typedef __attribute__((ext_vector_type(4))) float float4v;

__device__ __forceinline__ void ld4(const float* p, float* d) {
  float4 v = *(const float4*)p;
  d[0] = v.x; d[1] = v.y; d[2] = v.z; d[3] = v.w;
}
__device__ __forceinline__ void st4(float* p, const float* s) {
  *(float4*)p = make_float4(s[0], s[1], s[2], s[3]);
}
__device__ __forceinline__ float fastrcp(float x) {
  float r = __builtin_amdgcn_rcpf(x);
  return r * (2.0f - x * r);
}
__device__ __forceinline__ void mm4(float W[4][4], const float A[4][4], const float B[4][4]) {
  #pragma unroll
  for (int r = 0; r < 4; ++r)
    #pragma unroll
    for (int q = 0; q < 4; ++q) {
      float s = A[r][0]*B[0][q];
      #pragma unroll
      for (int k = 1; k < 4; ++k) s += A[r][k]*B[k][q];
      W[r][q] = s;
    }
}
__device__ __forceinline__ void inv4(float D[4][4]) {
  #pragma unroll
  for (int p = 0; p < 4; ++p) {
    float pi = fastrcp(D[p][p]);
    D[p][p] = pi;
    #pragma unroll
    for (int q = 0; q < 4; ++q) if (q != p) D[p][q] *= pi;
    #pragma unroll
    for (int i = 0; i < 4; ++i) if (i != p) {
      float f = D[i][p];
      #pragma unroll
      for (int q = 0; q < 4; ++q) if (q != p) D[i][q] -= f * D[p][q];
      D[i][p] = -f * pi;
    }
  }
}

// bf16 split helpers (RNE)
__device__ __forceinline__ unsigned short bf16h_rne(float v) {
  unsigned u = __float_as_uint(v);
  unsigned r = u + 0x7FFFu + ((u >> 16) & 1u);
  return (unsigned short)(r >> 16);
}
__device__ __forceinline__ float bf16_back(unsigned short h) {
  return __uint_as_float(((unsigned)h) << 16);
}
__device__ __forceinline__ void split8(const float v[8], short8v &hi, short8v &lo) {
  #pragma unroll
  for (int j = 0; j < 8; ++j) {
    unsigned short h = bf16h_rne(v[j]);
    float res = v[j] - bf16_back(h);
    unsigned short l = bf16h_rne(res);
    hi[j] = (short)h;
    lo[j] = (short)l;
  }
}

// double-buffered block-GJ step, stride 68 (64x64), 256 threads
__device__ __forceinline__ void gj_step64(const float* __restrict__ src,
                                          float* __restrict__ dst,
                                          int b, int ig, int jg) {
  float D[4][4], C[4][4], R[4][4], T4[4][4], W[4][4];
  #pragma unroll
  for (int r = 0; r < 4; ++r) {
    ld4(&src[(4*b + r)*68 + 4*b],  D[r]);
    ld4(&src[(4*ig + r)*68 + 4*b], C[r]);
    ld4(&src[(4*b + r)*68 + 4*jg], R[r]);
    ld4(&src[(4*ig + r)*68 + 4*jg], T4[r]);
  }
  inv4(D);
  if (ig == b) {
    if (jg == b) {
      #pragma unroll
      for (int r = 0; r < 4; ++r)
        #pragma unroll
        for (int q = 0; q < 4; ++q) W[r][q] = D[r][q];
    } else {
      mm4(W, D, R);
    }
  } else {
    float E[4][4];
    mm4(E, C, D);
    if (jg == b) {
      #pragma unroll
      for (int r = 0; r < 4; ++r)
        #pragma unroll
        for (int q = 0; q < 4; ++q) W[r][q] = -E[r][q];
    } else {
      #pragma unroll
      for (int r = 0; r < 4; ++r)
        #pragma unroll
        for (int q = 0; q < 4; ++q) {
          float s = T4[r][q];
          #pragma unroll
          for (int k = 0; k < 4; ++k) s -= E[r][k] * R[k][q];
          W[r][q] = s;
        }
    }
  }
  #pragma unroll
  for (int r = 0; r < 4; ++r) st4(&dst[(4*ig + r)*68 + 4*jg], W[r]);
  __syncthreads();
}

// double-buffered block-GJ step, stride 52 (48x48), threads 0..143
__device__ __forceinline__ void gj_step48(const float* __restrict__ src,
                                          float* __restrict__ dst,
                                          int b, int tid) {
  const bool act = tid < 144;
  const int ig = tid / 12, jg = tid - (tid / 12) * 12;
  float D[4][4], C[4][4], R[4][4], T4[4][4], W[4][4];
  if (act) {
    #pragma unroll
    for (int r = 0; r < 4; ++r) {
      ld4(&src[(4*b + r)*52 + 4*b],  D[r]);
      ld4(&src[(4*ig + r)*52 + 4*b], C[r]);
      ld4(&src[(4*b + r)*52 + 4*jg], R[r]);
      ld4(&src[(4*ig + r)*52 + 4*jg], T4[r]);
    }
    inv4(D);
    if (ig == b) {
      if (jg == b) {
        #pragma unroll
        for (int r = 0; r < 4; ++r)
          #pragma unroll
          for (int q = 0; q < 4; ++q) W[r][q] = D[r][q];
      } else {
        mm4(W, D, R);
      }
    } else {
      float E[4][4];
      mm4(E, C, D);
      if (jg == b) {
        #pragma unroll
        for (int r = 0; r < 4; ++r)
          #pragma unroll
          for (int q = 0; q < 4; ++q) W[r][q] = -E[r][q];
      } else {
        #pragma unroll
        for (int r = 0; r < 4; ++r)
          #pragma unroll
          for (int q = 0; q < 4; ++q) {
            float s = T4[r][q];
            #pragma unroll
            for (int k = 0; k < 4; ++k) s -= E[r][k] * R[k][q];
            W[r][q] = s;
          }
      }
    }
    #pragma unroll
    for (int r = 0; r < 4; ++r) st4(&dst[(4*ig + r)*52 + 4*jg], W[r]);
  }
  __syncthreads();
}

// ---------------------------------------------------------------- prep1
// Serial part: GJ64 -> T -> K2 -> GJ48. Writes S, T, Ki to workspace.
__global__ __launch_bounds__(256, 1) void prep1_kernel(
    const float* __restrict__ Qg, const float* __restrict__ Ag,
    const float* __restrict__ Gg,
    float* __restrict__ Sg, float* __restrict__ Tg, float* __restrict__ Kig)
{
  __shared__ float sMa[64*68];   // M1 ping -> S
  __shared__ float sMb[64*68];   // M1 pong -> T (stride 48)
  __shared__ float sK [48*52];   // K2 ping -> Ki
  __shared__ float sJx[48*68];   // Jx staged; also GJ48 pong (48*52)

#define SM_(i,j) sMa[(i)*68+(j)]
#define TT_(i,j) sMb[(i)*48+(j)]
#define SK_(i,j) sK[(i)*52+(j)]
#define JX_(a,k) sJx[(a)*68+(k)]

  const int tid = threadIdx.x;
  const int ig = tid >> 4, jg = tid & 15;

  // stage Jx = [A;G] and M1 = Q + I
  {
    const float4* A4 = (const float4*)Ag;
    const float4* G4 = (const float4*)Gg;
    {
      int a = tid >> 4, kc = tid & 15;
      float v[4]; ld4((const float*)&A4[tid], v);
      st4(&JX_(a, kc*4), v);
    }
    for (int t = tid; t < 512; t += 256) {
      int a = t >> 4, kc = t & 15;
      float v[4]; ld4((const float*)&G4[t], v);
      st4(&JX_(16 + a, kc*4), v);
    }
    const float4* Q4 = (const float4*)Qg;
    for (int t = tid; t < 1024; t += 256) {
      int i = t >> 4, kc = t & 15;
      float v[4]; ld4((const float*)&Q4[t], v);
      st4(&SM_(i, kc*4), v);
    }
  }
  __syncthreads();
  if (tid < 64) SM_(tid, tid) += 1.0f;
  __syncthreads();

  // block-GJ 64 (dbuf, 16 steps) -> S in sMa
  #pragma unroll 1
  for (int p = 0; p < 8; ++p) {
    gj_step64(sMa, sMb, 2*p,     ig, jg);
    gj_step64(sMb, sMa, 2*p + 1, ig, jg);
  }

  // T = S Jx^T : 4x3 register tile/thread
  {
    const int i0 = 4*ig, j0 = 3*jg;
    float acc[4][3] = {};
    #pragma unroll 4
    for (int kq = 0; kq < 16; ++kq) {
      float sv[4][4], jv[3][4];
      ld4(&SM_(i0+0, kq*4), sv[0]); ld4(&SM_(i0+1, kq*4), sv[1]);
      ld4(&SM_(i0+2, kq*4), sv[2]); ld4(&SM_(i0+3, kq*4), sv[3]);
      ld4(&JX_(j0+0, kq*4), jv[0]); ld4(&JX_(j0+1, kq*4), jv[1]);
      ld4(&JX_(j0+2, kq*4), jv[2]);
      #pragma unroll
      for (int r = 0; r < 4; ++r)
        #pragma unroll
        for (int c = 0; c < 3; ++c)
          #pragma unroll
          for (int s = 0; s < 4; ++s)
            acc[r][c] += sv[r][s] * jv[c][s];
    }
    __syncthreads();
    #pragma unroll
    for (int r = 0; r < 4; ++r)
      #pragma unroll
      for (int c = 0; c < 3; ++c)
        TT_(i0+r, j0+c) = acc[r][c];
  }
  __syncthreads();

  // K2 = Jx T + diag(0,I32)  (192 threads, 3x4 tiles)
  if (tid < 192) {
    int ag = tid / 12, bg = tid - ag*12;
    int a0 = ag*3, b0 = bg*4;
    float acc[3][4] = {};
    #pragma unroll 4
    for (int k = 0; k < 64; ++k) {
      float4 tb = *(const float4*)&TT_(k,b0);
      #pragma unroll
      for (int r = 0; r < 3; ++r) {
        float jv = JX_(a0 + r, k);
        acc[r][0] += jv*tb.x; acc[r][1] += jv*tb.y;
        acc[r][2] += jv*tb.z; acc[r][3] += jv*tb.w;
      }
    }
    #pragma unroll
    for (int r = 0; r < 3; ++r)
      #pragma unroll
      for (int q = 0; q < 4; ++q) {
        int a = a0 + r, b = b0 + q;
        SK_(a,b) = acc[r][q] + ((a == b && a >= 16) ? 1.0f : 0.0f);
      }
  }
  __syncthreads();

  // block-GJ 48 (dbuf; pong overlays dead Jx region) -> Ki in sK
  {
    float* KP = sJx;   // 48*52 = 2496 <= 48*68
    #pragma unroll 1
    for (int p = 0; p < 6; ++p) {
      gj_step48(sK, KP, 2*p,     tid);
      gj_step48(KP, sK, 2*p + 1, tid);
    }
  }

  // write S (64x64), T (64x48), Ki (48x48) to ws
  #pragma unroll 1
  for (int t = tid; t < 1024; t += 256) {
    int i = t >> 4, q = t & 15;
    float v[4]; ld4(&SM_(i, q*4), v); st4(&Sg[i*64 + q*4], v);
  }
  #pragma unroll 1
  for (int t = tid; t < 768; t += 256) {
    int i = t / 12, q = t - 12*(t/12);
    float v[4]; ld4(&TT_(i, q*4), v); st4(&Tg[i*48 + q*4], v);
  }
  #pragma unroll 1
  for (int t = tid; t < 576; t += 256) {
    int k = t / 12, q = t - 12*(t/12);
    float v[4]; ld4(&SK_(k, q*4), v); st4(&Kig[k*48 + q*4], v);
  }
#undef SM_
#undef TT_
#undef SK_
#undef JX_
}

// ---------------------------------------------------------------- prep2
// 4 blocks: each computes R2 (redundant, in LDS) + its 24-row slice of P/Bmat.
__global__ __launch_bounds__(256, 1) void prep2_kernel(
    const float* __restrict__ Sg, const float* __restrict__ Tg,
    const float* __restrict__ Kig,
    float* __restrict__ Pg, float* __restrict__ Bg)
{
  __shared__ float sT [64*48];
  __shared__ float sKi[48*48];
  __shared__ float sR2[48*96];
  __shared__ float sS [24*64];

  const int tid = threadIdx.x;
  const int b   = blockIdx.x;        // 0..3, rows [24b, 24b+24)
  const int r0b = 24 * b;

  // stage T (768 quads), Ki (576), S-slice (384, only rows < 64)
  #pragma unroll 1
  for (int t = tid; t < 768; t += 256) {
    float v[4]; ld4(&Tg[t*4], v); st4(&sT[t*4], v);
  }
  #pragma unroll 1
  for (int t = tid; t < 576; t += 256) {
    float v[4]; ld4(&Kig[t*4], v); st4(&sKi[t*4], v);
  }
  #pragma unroll 1
  for (int t = tid; t < 384; t += 256) {
    int ri = t >> 4, q = t & 15;
    if (r0b + ri < 64) {
      float v[4]; ld4(&Sg[(r0b + ri)*64 + q*4], v); st4(&sS[ri*64 + q*4], v);
    }
  }
  __syncthreads();

  // R2 cols<64: R2[k][c] = sum_m Ki[k][m]*T[c][m]
  #pragma unroll 1
  for (int t = tid; t < 48*64; t += 256) {
    int k = t >> 6, c = t & 63;
    float acc = 0.0f;
    #pragma unroll 4
    for (int m = 0; m < 48; m += 4) {
      float kv[4], tv[4];
      ld4(&sKi[k*48 + m], kv); ld4(&sT[c*48 + m], tv);
      acc += kv[0]*tv[0] + kv[1]*tv[1] + kv[2]*tv[2] + kv[3]*tv[3];
    }
    sR2[k*96 + c] = acc;
  }
  // R2 cols>=64 (selection from Ki)
  #pragma unroll 1
  for (int t = tid; t < 48*32; t += 256) {
    int k = t >> 5, j = t & 31;
    sR2[k*96 + 64 + j] = sKi[k*48 + 16 + j];
  }
  __syncthreads();

  // Bmat right slice: Bg[c][64+k] = R2[k][c] for c in [24b, 24b+24)
  #pragma unroll 1
  for (int t = tid; t < 24*48; t += 256) {
    int c = r0b + t / 48, k = t - 48*(t/48);
    Bg[c*112 + 64 + k] = sR2[k*96 + c];
  }

  // P slice rows [24b, 24b+24): heavy (i<64) or light (i>=64)
  #pragma unroll 1
  for (int task = tid; task < 576; task += 256) {
    int ri = task / 24, jq = task - 24*(task/24);
    int i = r0b + ri, j0 = jq*4;
    if (i < 64) {
      float acc[4];
      #pragma unroll
      for (int q = 0; q < 4; ++q)
        acc[q] = (j0 < 64) ? sS[ri*64 + j0 + q] : 0.0f;
      #pragma unroll 4
      for (int m = 0; m < 48; m += 4) {
        float tv[4], rv[4][4];
        ld4(&sT[i*48 + m], tv);
        ld4(&sR2[(m+0)*96 + j0], rv[0]);
        ld4(&sR2[(m+1)*96 + j0], rv[1]);
        ld4(&sR2[(m+2)*96 + j0], rv[2]);
        ld4(&sR2[(m+3)*96 + j0], rv[3]);
        #pragma unroll
        for (int q = 0; q < 4; ++q)
          #pragma unroll
          for (int s = 0; s < 4; ++s)
            acc[q] -= tv[s] * rv[s][q];
      }
      #pragma unroll
      for (int q = 0; q < 4; ++q) {
        int j = j0 + q;
        Pg[i*96 + j] = acc[q];
        if (j < 64) Bg[i*112 + j] = -acc[q];
      }
    } else {
      int a = i - 64;
      #pragma unroll
      for (int q = 0; q < 4; ++q) {
        int j = j0 + q;
        float v = (i == j ? 1.0f : 0.0f) - sR2[(16 + a)*96 + j];
        Pg[i*96 + j] = v;
        if (j < 64) Bg[i*112 + j] = -v;
      }
    }
  }
}

// ---------------------------------------------------------------- kernel B
#define EB 16   // elements per block; grid = 256 blocks x 384 threads (6 waves)

__global__ __launch_bounds__(384, 1) void iter_kernel(
    const float* __restrict__ xg, const float* __restrict__ pg,
    const float* __restrict__ Pg, const float* __restrict__ Bg,
    float* __restrict__ outg)
{
  // MFMA formulation: Y[96][16] = P[96][96] @ X[96][16] in split-bf16.
  // Wave w owns row-tile 16w. 3 independent MFMA chains (one per kc).
  __shared__ float sX[2][EB][100];
  __shared__ float sPar[EB][128];   // parms padded to K=128 with zeros

  const int tid   = threadIdx.x;    // 0..383
  const int gbase = blockIdx.x * EB;
  const int w     = tid >> 6;
  const int lane  = tid & 63;
  const int e     = lane & 15;
  const int g     = lane >> 4;
  const int row0  = 16 * w;

  {
    int ee = tid / 24, kc = tid - 24 * (tid / 24);
    *(float4*)&sX[0][ee][kc*4] = ((const float4*)xg)[gbase*24 + tid];
  }
  for (int t = tid; t < EB*28; t += 384) {
    int ee = t / 28, jc = t - 28 * (t / 28);
    *(float4*)&sPar[ee][jc*4] = ((const float4*)pg)[gbase*28 + t];
  }
  if (tid < EB*4) {
    int ee = tid >> 2, jc = tid & 3;
    *(float4*)&sPar[ee][112 + jc*4] = make_float4(0.f, 0.f, 0.f, 0.f);
  }

  // P fragments (A operand), hi/lo, register-resident
  short8v pfh[3], pfl[3];
  #pragma unroll
  for (int kc = 0; kc < 3; ++kc) {
    float v[8];
    const float* src = Pg + (row0 + e)*96 + 32*kc + 8*g;
    ld4(src, v); ld4(src + 4, v + 4);
    split8(v, pfh[kc], pfl[kc]);
  }

  __syncthreads();

  // c = Bmat @ parms via MFMA (K=112 zero-padded to 128)
  float4v cfrag = {0.f, 0.f, 0.f, 0.f};
  #pragma unroll
  for (int kc = 0; kc < 4; ++kc) {
    const int kbase = 32*kc + 8*g;
    float v[8];
    short8v ah, al, bh, bl;
    if (kbase < 112) {
      const float* src = Bg + (row0 + e)*112 + kbase;
      ld4(src, v); ld4(src + 4, v + 4);
    } else {
      #pragma unroll
      for (int j = 0; j < 8; ++j) v[j] = 0.f;
    }
    split8(v, ah, al);
    ld4(&sPar[e][kbase], v); ld4(&sPar[e][kbase + 4], v + 4);
    split8(v, bh, bl);
    cfrag = __builtin_amdgcn_mfma_f32_16x16x32_bf16(ah, bh, cfrag, 0, 0, 0);
    cfrag = __builtin_amdgcn_mfma_f32_16x16x32_bf16(ah, bl, cfrag, 0, 0, 0);
    cfrag = __builtin_amdgcn_mfma_f32_16x16x32_bf16(al, bh, cfrag, 0, 0, 0);
  }

  const float lob = (row0 < 64) ? -1000.f : 0.f;
  float* curb = &sX[0][0][0];
  float* nxtb = &sX[1][0][0];

  #pragma unroll 1
  for (int it = 0; it < 10; ++it) {
    // x fragments (B operand), split-bf16
    short8v xh[3], xl[3];
    #pragma unroll
    for (int kc = 0; kc < 3; ++kc) {
      float v[8];
      const float* src = curb + e*100 + 32*kc + 8*g;
      ld4(src, v); ld4(src + 4, v + 4);
      split8(v, xh[kc], xl[kc]);
    }
    // 3 independent accumulation chains (depth 3 instead of 9)
    float4v accs[3];
    accs[0] = cfrag;
    accs[1] = (float4v){0.f, 0.f, 0.f, 0.f};
    accs[2] = (float4v){0.f, 0.f, 0.f, 0.f};
    #pragma unroll
    for (int kc = 0; kc < 3; ++kc) {
      accs[kc] = __builtin_amdgcn_mfma_f32_16x16x32_bf16(pfh[kc], xh[kc], accs[kc], 0, 0, 0);
      accs[kc] = __builtin_amdgcn_mfma_f32_16x16x32_bf16(pfh[kc], xl[kc], accs[kc], 0, 0, 0);
      accs[kc] = __builtin_amdgcn_mfma_f32_16x16x32_bf16(pfl[kc], xh[kc], accs[kc], 0, 0, 0);
    }
    float4v acc = accs[0] + accs[1] + accs[2];

    if (it < 9) {
      #pragma unroll
      for (int r = 0; r < 4; ++r) {
        int row = row0 + 4*g + r;
        float y  = acc[r];
        float xo = curb[e*100 + row];
        float z  = fminf(fmaxf(2.f*y - xo, lob), 1000.f);
        nxtb[e*100 + row] = xo + z - y;
      }
      __syncthreads();
      float* t2 = curb; curb = nxtb; nxtb = t2;
    } else {
      if (row0 < 64) {
        *(float4*)&outg[(gbase + e)*64 + row0 + 4*g] =
            make_float4(acc[0], acc[1], acc[2], acc[3]);
      }
    }
  }
}

// ---------------------------------------------------------------- launch
extern "C" void kernel_launch(void* const* d_in, const int* in_sizes, int n_in,
                              void* d_out, int out_size, void* d_ws, size_t ws_size,
                              hipStream_t stream) {
  const float* x     = (const float*)d_in[0];   // (4096, 96)
  const float* parms = (const float*)d_in[1];   // (4096, 112)
  const float* Qg    = (const float*)d_in[2];   // (64, 64)
  const float* Ag    = (const float*)d_in[3];   // (16, 64)
  const float* Gg    = (const float*)d_in[4];   // (32, 64)
  float* out = (float*)d_out;                   // (4096, 64)

  float* ws  = (float*)d_ws;
  float* Pg  = ws;                  // 96*96  = 9216
  float* Bg  = ws + 9216;           // 96*112 = 10752
  float* Sg  = ws + 19968;          // 64*64  = 4096
  float* Tg  = ws + 24064;          // 64*48  = 3072
  float* Kig = ws + 27136;          // 48*48  = 2304

  prep1_kernel<<<1, 256, 0, stream>>>(Qg, Ag, Gg, Sg, Tg, Kig);
  prep2_kernel<<<4, 256, 0, stream>>>(Sg, Tg, Kig, Pg, Bg);
  iter_kernel<<<4096 / EB, 384, 0, stream>>>(x, parms, Pg, Bg, out);
}